// Round 4
// baseline (172.292 us; speedup 1.0000x reference)
//
#include <hip/hip_runtime.h>

// LBP block — row-streaming kernel, one channel per wave, 32-row strip.
// R4 restructure: the old layout (wave = 2 rows x 16-channel loop) pinned
// xr[4][3] (48 VGPRs) across the whole kernel and with unroll-4 sat at
// ~160-190 VGPRs -> 2 waves/SIMD; kernel ran ~65us vs ~23us write roofline.
// R3 proved DS-shuffle latency wasn't the stall; R2 proved capping THIS
// structure spills. New structure reaches low pressure naturally:
//   wave = (n, channel o, 32-row strip). Rolling 4-slot y-window, 2 x-row
//   prefetch buffers, e/conv_w loaded once per wave, y computed once per row
//   (1.06x conv redundancy vs 2x), no LDS, no __syncthreads.
// Channel-0 waves also emit the 3 x-copy planes from their loaded x rows.
//
// Numerics (do not change): y = (x0*cw0 + x1*cw1) + x2*cw2 sequentially with
// FMA contraction OFF to match the reference; (c - s > 0) == (c > s) exactly
// for finite floats. Halo via DPP wavefront shifts (R3-verified bit-identical):
//   wave_shr:1 -> lane i gets lane i-1 (== __shfl_up 1), lane 0 gets old=0
//   wave_shl:1 -> lane i gets lane i+1 (== __shfl_down 1), lane 63 gets old=0
// Out rows 0/255 and cols 0/255 of LBP channels are zero (reference pads).

__device__ __forceinline__ float wave_shr1(float v) {   // lane i <- lane i-1
    return __int_as_float(
        __builtin_amdgcn_update_dpp(0, __float_as_int(v), 0x138, 0xf, 0xf, false));
}
__device__ __forceinline__ float wave_shl1(float v) {   // lane i <- lane i+1
    return __int_as_float(
        __builtin_amdgcn_update_dpp(0, __float_as_int(v), 0x130, 0xf, 0xf, false));
}

// Load x row ROW (clamped) for all 3 input channels into BUF[3] (float4 each).
#define LOAD3(BUF, ROW) do {                                                  \
    int _r = (ROW); _r = _r < 0 ? 0 : (_r > 255 ? 255 : _r);                  \
    const float* _p = xn + (size_t)_r * 256 + col;                            \
    BUF[0] = *(const float4*)(_p);                                            \
    BUF[1] = *(const float4*)(_p + 65536);                                    \
    BUF[2] = *(const float4*)(_p + 131072);                                   \
} while (0)

// conv: y row from BUF into window slot SLOT (SLOT must fold to a constant).
#define CONV_ROW(BUF, SLOT) do {                                              \
    float4 _y;                                                                \
    _y.x = BUF[0].x * cw0 + BUF[1].x * cw1 + BUF[2].x * cw2;                  \
    _y.y = BUF[0].y * cw0 + BUF[1].y * cw1 + BUF[2].y * cw2;                  \
    _y.z = BUF[0].z * cw0 + BUF[1].z * cw1 + BUF[2].z * cw2;                  \
    _y.w = BUF[0].w * cw0 + BUF[1].w * cw1 + BUF[2].w * cw2;                  \
    Y[SLOT][1] = _y.x; Y[SLOT][2] = _y.y; Y[SLOT][3] = _y.z; Y[SLOT][4] = _y.w; \
    Y[SLOT][0] = wave_shr1(_y.w);                                             \
    Y[SLOT][5] = wave_shl1(_y.x);                                             \
} while (0)

// channel-0 wave: copy x row ROW (3 planes) to the output's first 3 channels.
#define COPYX(BUF, ROW) do {                                                  \
    float* _cp = outn + (size_t)(ROW) * 256 + col;                            \
    *(float4*)(_cp)          = BUF[0];                                        \
    *(float4*)(_cp + 65536)  = BUF[1];                                        \
    *(float4*)(_cp + 131072) = BUF[2];                                        \
} while (0)

// Emit output row R using window slots SU (y[R-1]), SM (y[R]), SD (y[R+1]).
#define EMIT(R, SU, SM, SD) do {                                              \
    const int _row = (R);                                                     \
    float res0, res1, res2, res3;                                             \
    if (_row == 0 || _row == 255) {                                           \
        res0 = res1 = res2 = res3 = 0.f;                                      \
    } else {                                                                  \
        res0 = res1 = res2 = res3 = 0.f;  /* overwritten below */             \
        float _r[4];                                                          \
        _Pragma("unroll")                                                     \
        for (int _j = 0; _j < 4; ++_j) {                                      \
            const float _c = Y[SM][_j + 1];                                   \
            float _a;                                                         \
            _a  = (_c > Y[SU][_j    ]) ? e0 : 0.f;                            \
            _a += (_c > Y[SU][_j + 1]) ? e1 : 0.f;                            \
            _a += (_c > Y[SU][_j + 2]) ? e2 : 0.f;                            \
            _a += (_c > Y[SM][_j    ]) ? e3 : 0.f;                            \
            _a += (_c > Y[SD][_j    ]) ? e4 : 0.f;                            \
            _a += (_c > Y[SD][_j + 1]) ? e5 : 0.f;                            \
            _a += (_c > Y[SD][_j + 2]) ? e6 : 0.f;                            \
            _a += (_c > Y[SM][_j + 2]) ? e7 : 0.f;                            \
            _r[_j] = _a;                                                      \
        }                                                                     \
        res0 = _r[0]; res1 = _r[1]; res2 = _r[2]; res3 = _r[3];               \
        if (lane == 0)  res0 = 0.f;                                           \
        if (lane == 63) res3 = 0.f;                                           \
    }                                                                         \
    *(float4*)(ob + (size_t)_row * 256 + col) =                               \
        make_float4(res0, res1, res2, res3);                                  \
} while (0)

__global__ __launch_bounds__(256) void lbp_all(
    const float* __restrict__ x,
    const float* __restrict__ conv_w,
    const float* __restrict__ w,
    float* __restrict__ out)
{
#pragma clang fp contract(off)
    const int n    = blockIdx.z;
    const int o    = blockIdx.y * 4 + (threadIdx.x >> 6);  // channel 0..63
    const int lane = threadIdx.x & 63;
    const int col  = lane * 4;
    const int s0   = blockIdx.x * 32;                      // strip's first row
    const bool copyx = (o == 0);

    const float cw0 = conv_w[o * 3 + 0];
    const float cw1 = conv_w[o * 3 + 1];
    const float cw2 = conv_w[o * 3 + 2];

    // exp(w) once per wave; wave-uniform -> hoist to SGPRs.
    const float e0 = __uint_as_float(__builtin_amdgcn_readfirstlane(__float_as_uint(expf(w[o * 8 + 0]))));
    const float e1 = __uint_as_float(__builtin_amdgcn_readfirstlane(__float_as_uint(expf(w[o * 8 + 1]))));
    const float e2 = __uint_as_float(__builtin_amdgcn_readfirstlane(__float_as_uint(expf(w[o * 8 + 2]))));
    const float e3 = __uint_as_float(__builtin_amdgcn_readfirstlane(__float_as_uint(expf(w[o * 8 + 3]))));
    const float e4 = __uint_as_float(__builtin_amdgcn_readfirstlane(__float_as_uint(expf(w[o * 8 + 4]))));
    const float e5 = __uint_as_float(__builtin_amdgcn_readfirstlane(__float_as_uint(expf(w[o * 8 + 5]))));
    const float e6 = __uint_as_float(__builtin_amdgcn_readfirstlane(__float_as_uint(expf(w[o * 8 + 6]))));
    const float e7 = __uint_as_float(__builtin_amdgcn_readfirstlane(__float_as_uint(expf(w[o * 8 + 7]))));

    const float* xn   = x + (size_t)n * 3 * 65536;
    float* outn       = out + (size_t)n * 67 * 65536;      // channels 0..2 = x copy
    float* ob         = outn + (size_t)(3 + o) * 65536;    // this wave's LBP plane

    float4 bA[3], bB[3];
    float  Y[4][6];   // rolling y-window; all indices fold to constants

    // Prologue: y[s0-1] -> slot 3, y[s0] -> slot 0; prefetch row s0+1.
    LOAD3(bA, s0 - 1);
    LOAD3(bB, s0);
    CONV_ROW(bA, 3);
    CONV_ROW(bB, 0);
    if (copyx) COPYX(bB, s0);
    LOAD3(bA, s0 + 1);

    // 32 emissions: j = 0..31, output row r = s0+j.
    // Slot rotation period 4, buffer parity period 2 -> explicit 4-step body.
#define STEP(JI) do {                                                         \
    const int j = jo4 + (JI);                                                 \
    if (((JI) & 1) == 0) {                                                    \
        if (j < 31) LOAD3(bB, s0 + j + 2);                                    \
        CONV_ROW(bA, ((JI) + 1) & 3);                                         \
        if (copyx && j < 31) COPYX(bA, s0 + j + 1);                           \
    } else {                                                                  \
        if (j < 31) LOAD3(bA, s0 + j + 2);                                    \
        CONV_ROW(bB, ((JI) + 1) & 3);                                         \
        if (copyx && j < 31) COPYX(bB, s0 + j + 1);                           \
    }                                                                         \
    EMIT(s0 + j, ((JI) + 3) & 3, (JI) & 3, ((JI) + 1) & 3);                   \
} while (0)

    for (int jo4 = 0; jo4 < 32; jo4 += 4) {
        STEP(0); STEP(1); STEP(2); STEP(3);
    }
#undef STEP
}

extern "C" void kernel_launch(void* const* d_in, const int* in_sizes, int n_in,
                              void* d_out, int out_size, void* d_ws, size_t ws_size,
                              hipStream_t stream) {
    const float* x      = (const float*)d_in[0];
    const float* conv_w = (const float*)d_in[1];
    const float* w      = (const float*)d_in[2];
    float* out          = (float*)d_out;

    // (8 row-strips of 32, 16 channel-groups of 4 waves, 8 batch)
    dim3 grid(8, 16, 8);
    dim3 block(256);
    hipLaunchKernelGGL(lbp_all, grid, block, 0, stream, x, conv_w, w, out);
}

// Round 5
// 154.219 us; speedup vs baseline: 1.1172x; 1.1172x over previous
//
#include <hip/hip_runtime.h>

// LBP block — fused kernel, 2 output rows per wave, 16-channel loop.
// block = 256 threads (4 waves) = (n, 8-row tile, group of 16 channels).
//
// R5 (occupancy via NATURAL pressure reduction; R2 proved capping spills,
// R4 proved streaming-with-loads-on-critical-path loses):
//  - x-tile (10 rows x 3ch, clamped) staged in LDS once per block (30 KB),
//    cooperatively loaded; frees the 48 VGPRs xr[4][3] pinned. Per channel
//    each wave re-reads its 4 rows x 3ch as ds_read_b128 (wave-uniform row,
//    contiguous 16B/lane = conflict-free pattern).
//  - unroll 1 on the channel loop: no cross-channel live-state duplication;
//    4 waves/SIMD TLP hides latency instead of ILP.
//  - LBP accumulation as pairwise tree (dep depth 16 -> ~5). Only the OUTER
//    sum of selected e's is reassociated; heaviside decisions are computed
//    from the identical contract-off conv values, so diffs are rounding-level.
//  - DPP wavefront shifts for the halo (R3-verified bit-identical).
// Whole grid (1024 blocks) is now co-resident: LDS 4x30.5KB=122KB/CU,
// est. ~80 VGPR -> 4 waves/SIMD.
//
// Numerics: y = (x0*cw0 + x1*cw1) + x2*cw2 sequentially with FMA contraction
// OFF (heaviside inputs must match reference); (c - s > 0) == (c > s) for
// finite floats. Out rows 0/255 and cols 0/255 of LBP channels are zero.

__device__ __forceinline__ float wave_shr1(float v) {   // lane i <- lane i-1
    return __int_as_float(
        __builtin_amdgcn_update_dpp(0, __float_as_int(v), 0x138, 0xf, 0xf, false));
}
__device__ __forceinline__ float wave_shl1(float v) {   // lane i <- lane i+1
    return __int_as_float(
        __builtin_amdgcn_update_dpp(0, __float_as_int(v), 0x130, 0xf, 0xf, false));
}

__global__ __launch_bounds__(256) void lbp_all(
    const float* __restrict__ x,
    const float* __restrict__ conv_w,
    const float* __restrict__ w,
    float* __restrict__ out)
{
#pragma clang fp contract(off)
    const int n    = blockIdx.z;
    const int og   = blockIdx.y;             // channels og*16 .. og*16+15
    const int tid  = threadIdx.x;
    const int lane = tid & 63;
    const int wv   = tid >> 6;               // wave 0..3
    const int col  = lane * 4;
    const int R    = blockIdx.x * 8;         // block's first output row
    const int hrow0 = R + wv * 2;            // wave's first output row

    __shared__ float xt[3][10][256];         // x rows R-1..R+8 (clamped), 30 KB
    __shared__ float ews[128];               // exp(w) for this block's 16 ch

    if (tid < 128) ews[tid] = expf(w[og * 128 + tid]);

    const float* xn = x + (size_t)n * 3 * 65536;

    // Cooperative x-tile load: 1920 float4s (3ch x 10 rows x 64 lanes).
    for (int f = tid; f < 1920; f += 256) {
        const int ch = f / 640;              // 640 float4s per channel
        const int rr = (f - ch * 640) >> 6;  // LDS row 0..9
        const int l4 = f & 63;
        int gr = R - 1 + rr;
        gr = gr < 0 ? 0 : (gr > 255 ? 255 : gr);
        *(float4*)&xt[ch][rr][l4 * 4] =
            *(const float4*)(xn + (size_t)ch * 65536 + (size_t)gr * 256 + l4 * 4);
    }
    __syncthreads();

    if (og == 0) {  // copy channels 0..2 from LDS rows 2wv+1, 2wv+2
        #pragma unroll
        for (int ch = 0; ch < 3; ++ch) {
            float* cp = out + ((((size_t)n * 67 + ch) * 256 + hrow0) * 256 + col);
            *(float4*)cp         = *(const float4*)&xt[ch][2 * wv + 1][col];
            *(float4*)(cp + 256) = *(const float4*)&xt[ch][2 * wv + 2][col];
        }
    }

    float* obase = out + ((((size_t)n * 67 + 3 + og * 16) * 256 + hrow0) * 256 + col);

    #pragma unroll 1
    for (int oi = 0; oi < 16; ++oi) {
        const int o = og * 16 + oi;
        const float cw0 = conv_w[o * 3 + 0];
        const float cw1 = conv_w[o * 3 + 1];
        const float cw2 = conv_w[o * 3 + 2];

        const float e0 = ews[oi * 8 + 0], e1 = ews[oi * 8 + 1];
        const float e2 = ews[oi * 8 + 2], e3 = ews[oi * 8 + 3];
        const float e4 = ews[oi * 8 + 4], e5 = ews[oi * 8 + 5];
        const float e6 = ews[oi * 8 + 6], e7 = ews[oi * 8 + 7];

        // Y[r][k] = y at global row hrow0-1+r (= LDS row 2wv+r), col col-1+k.
        float Y[4][6];
        #pragma unroll
        for (int r = 0; r < 4; ++r) {
            const int lr = 2 * wv + r;       // wave-uniform LDS row
            const float4 a = *(const float4*)&xt[0][lr][col];
            const float4 b = *(const float4*)&xt[1][lr][col];
            const float4 c = *(const float4*)&xt[2][lr][col];
            float4 yv;
            yv.x = a.x * cw0 + b.x * cw1 + c.x * cw2;
            yv.y = a.y * cw0 + b.y * cw1 + c.y * cw2;
            yv.z = a.z * cw0 + b.z * cw1 + c.z * cw2;
            yv.w = a.w * cw0 + b.w * cw1 + c.w * cw2;
            Y[r][1] = yv.x; Y[r][2] = yv.y; Y[r][3] = yv.z; Y[r][4] = yv.w;
            Y[r][0] = wave_shr1(yv.w);       // lane 0 gets 0 -> col 0 zeroed
            Y[r][5] = wave_shl1(yv.x);       // lane 63 gets 0 -> col 255 zeroed
        }

        #pragma unroll
        for (int k = 0; k < 2; ++k) {        // the wave's two output rows
            const int hrow = hrow0 + k;
            float res[4];
            if (hrow == 0 || hrow == 255) {  // wave-uniform branch
                res[0] = res[1] = res[2] = res[3] = 0.f;
            } else {
                const float* up  = Y[k];
                const float* mid = Y[k + 1];
                const float* dn  = Y[k + 2];
                #pragma unroll
                for (int j = 0; j < 4; ++j) {
                    const float c = mid[j + 1];
                    const float n0 = (c > up [j    ]) ? e0 : 0.f;  // (-1,-1)
                    const float n1 = (c > up [j + 1]) ? e1 : 0.f;  // (-1, 0)
                    const float n2 = (c > up [j + 2]) ? e2 : 0.f;  // (-1,+1)
                    const float n3 = (c > mid[j    ]) ? e3 : 0.f;  // ( 0,-1)
                    const float n4 = (c > dn [j    ]) ? e4 : 0.f;  // (+1,-1)
                    const float n5 = (c > dn [j + 1]) ? e5 : 0.f;  // (+1, 0)
                    const float n6 = (c > dn [j + 2]) ? e6 : 0.f;  // (+1,+1)
                    const float n7 = (c > mid[j + 2]) ? e7 : 0.f;  // ( 0,+1)
                    res[j] = ((n0 + n1) + (n2 + n3)) + ((n4 + n5) + (n6 + n7));
                }
                if (lane == 0)  res[0] = 0.f;   // col 0
                if (lane == 63) res[3] = 0.f;   // col 255
            }
            *(float4*)(obase + (size_t)oi * 65536 + (size_t)k * 256) =
                make_float4(res[0], res[1], res[2], res[3]);
        }
    }
}

extern "C" void kernel_launch(void* const* d_in, const int* in_sizes, int n_in,
                              void* d_out, int out_size, void* d_ws, size_t ws_size,
                              hipStream_t stream) {
    const float* x      = (const float*)d_in[0];
    const float* conv_w = (const float*)d_in[1];
    const float* w      = (const float*)d_in[2];
    float* out          = (float*)d_out;

    dim3 grid(32, 4, 8);   // (8-row tiles, channel groups of 16, batch)
    dim3 block(256);
    hipLaunchKernelGGL(lbp_all, grid, block, 0, stream, x, conv_w, w, out);
}